// Round 3
// baseline (8278.388 us; speedup 1.0000x reference)
//
#include <hip/hip_runtime.h>
#include <math.h>

#define NN 50000
#define EE 800000
#define TT 24
#define INF 11
#define HID 128

static constexpr int KTOT = 280;   // 12(x) + 12(xl) + 128(h) + 128(hl), padded
#define BM 64
#define BN 128
#define BK 8

// fast device math: v_exp_f32-based sigmoid/tanh, saturation-safe
__device__ __forceinline__ float fast_sigmoid(float v) {
    float e = __expf(-v);                       // v<<0 -> inf, v>>0 -> 0
    return __builtin_amdgcn_rcpf(1.0f + e);     // rcp(inf)=0, rcp(1)=1
}
__device__ __forceinline__ float fast_tanh(float v) {
    float e2 = __expf(2.0f * v);                // v>>0 -> inf, v<<0 -> 0
    return 1.0f - 2.0f * __builtin_amdgcn_rcpf(e2 + 1.0f);  // -> +1 / -1
}

// ---------------- preprocessing kernels ----------------

__global__ void count_deg_kernel(const int* __restrict__ src, const int* __restrict__ dst,
                                 int* __restrict__ deg_src, int* __restrict__ cnt_dst) {
    int e = blockIdx.x * blockDim.x + threadIdx.x;
    if (e < EE) {
        atomicAdd(&deg_src[src[e]], 1);
        atomicAdd(&cnt_dst[dst[e]], 1);
    }
}

__global__ void dinv_kernel(const int* __restrict__ deg, float* __restrict__ dinv) {
    int i = blockIdx.x * blockDim.x + threadIdx.x;
    if (i < NN) {
        int d = deg[i];
        dinv[i] = (d > 0) ? 1.0f / sqrtf((float)d) : 0.0f;
    }
}

// single-block scan over cnt -> exclusive prefix (row_ptr), row_ptr[NN] = E
__global__ void scan_kernel(const int* __restrict__ cnt, int* __restrict__ row_ptr) {
    __shared__ int buf[2][1024];
    __shared__ int carry_s;
    int tid = threadIdx.x;
    if (tid == 0) carry_s = 0;
    __syncthreads();
    for (int base = 0; base < NN; base += 1024) {
        int i = base + tid;
        int v = (i < NN) ? cnt[i] : 0;
        int pb = 0;
        buf[0][tid] = v;
        __syncthreads();
        for (int off = 1; off < 1024; off <<= 1) {
            int t = buf[pb][tid] + ((tid >= off) ? buf[pb][tid - off] : 0);
            buf[pb ^ 1][tid] = t;
            pb ^= 1;
            __syncthreads();
        }
        int incl = buf[pb][tid];
        int carry = carry_s;
        if (i < NN) row_ptr[i] = carry + incl - v;
        __syncthreads();
        if (tid == 0) carry_s = carry + buf[pb][1023];
        __syncthreads();
    }
    if (tid == 0) row_ptr[NN] = carry_s;
}

// CSR entry packed as int2 {src, float_bits(w)} -> one 8B load per edge in the laps
__global__ void fill_csr_kernel(const int* __restrict__ src, const int* __restrict__ dst,
                                const int* __restrict__ row_ptr, int* __restrict__ fillp,
                                const float* __restrict__ dinv,
                                int2* __restrict__ csr) {
    int e = blockIdx.x * blockDim.x + threadIdx.x;
    if (e < EE) {
        int s = src[e], d = dst[e];
        int p = row_ptr[d] + atomicAdd(&fillp[d], 1);
        float w = -(dinv[s] * dinv[d]);
        csr[p] = make_int2(s, __float_as_int(w));
    }
}

// pack Wx/Wh into WA [280][256] (gates z,r) and WB [280][128] (gate h~), biases summed
__global__ void pack_weights_kernel(const float* __restrict__ Wx, const float* __restrict__ bx,
                                    const float* __restrict__ Wh, const float* __restrict__ bh,
                                    float* __restrict__ WA, float* __restrict__ biasA,
                                    float* __restrict__ WB, float* __restrict__ biasB) {
    int idx = blockIdx.x * blockDim.x + threadIdx.x;
    const int NA = 280 * 256, NB = 280 * 128;
    if (idx < NA) {
        int k = idx / 256, j = idx % 256;
        int g = j >> 7, jj = j & 127;
        float v = 0.0f;
        if (k < 12)       { if (k < 11)      v = Wx[((g*2 + 0)*11 + k)      * 128 + jj]; }
        else if (k < 24)  { int kk = k - 12; if (kk < 11) v = Wx[((g*2 + 1)*11 + kk) * 128 + jj]; }
        else if (k < 152) { int kk = k - 24;  v = Wh[((g*2 + 0)*128 + kk) * 128 + jj]; }
        else              { int kk = k - 152; v = Wh[((g*2 + 1)*128 + kk) * 128 + jj]; }
        WA[idx] = v;
    } else if (idx < NA + NB) {
        int t = idx - NA;
        int k = t / 128, jj = t % 128;
        float v = 0.0f;
        if (k < 12)       { if (k < 11)      v = Wx[(4*11 + k)  * 128 + jj]; }
        else if (k < 24)  { int kk = k - 12; if (kk < 11) v = Wx[(5*11 + kk) * 128 + jj]; }
        else if (k < 152) { int kk = k - 24;  v = Wh[(4*128 + kk) * 128 + jj]; }
        else              { int kk = k - 152; v = Wh[(5*128 + kk) * 128 + jj]; }
        WB[t] = v;
    } else if (idx < NA + NB + 256) {
        int j = idx - (NA + NB);
        int g = j >> 7, jj = j & 127;
        biasA[j] = bx[g*128 + jj] + bh[g*128 + jj];
    } else if (idx < NA + NB + 256 + 128) {
        int jj = idx - (NA + NB + 256);
        biasB[jj] = bx[2*128 + jj] + bh[2*128 + jj];
    }
}

// ---------------- per-step kernels ----------------

__global__ void copy_x0_kernel(const float* __restrict__ X0, float* __restrict__ x) {
    int i = blockIdx.x * blockDim.x + threadIdx.x;
    if (i < NN) {
        #pragma unroll
        for (int c = 0; c < 11; c++) x[i*12 + c] = X0[i*11 + c];
        x[i*12 + 11] = 0.0f;
    }
}

// x = [X_t[:, :3], pos, X_t[:, 6:8], (pos - prev)/dt]  (pad col 11 = 0)
__global__ void build_x_kernel(const float* __restrict__ Xt, const float* __restrict__ Xtm1,
                               const float* __restrict__ pos, const float* __restrict__ prevbase,
                               int prev_stride, int prev_off, float* __restrict__ x) {
    int i = blockIdx.x * blockDim.x + threadIdx.x;
    if (i >= NN) return;
    const float* xo = Xt + (size_t)i * 11;
    float tnow  = xo[6];
    float tprev = Xtm1[(size_t)i * 11 + 6];
    float inv = 1.0f / (tnow - tprev);
    float p0 = pos[(size_t)i*3 + 0], p1 = pos[(size_t)i*3 + 1], p2 = pos[(size_t)i*3 + 2];
    const float* pp = prevbase + (size_t)i * prev_stride + prev_off;
    float q0 = pp[0], q1 = pp[1], q2 = pp[2];
    float* xr = x + (size_t)i * 12;
    xr[0] = xo[0]; xr[1] = xo[1]; xr[2] = xo[2];
    xr[3] = p0;    xr[4] = p1;    xr[5] = p2;
    xr[6] = tnow;  xr[7] = xo[7];
    xr[8] = (p0 - q0) * inv; xr[9] = (p1 - q1) * inv; xr[10] = (p2 - q2) * inv;
    xr[11] = 0.0f;
}

// xl = L_hat @ x  for F=12 (padded); 16 threads per node
__global__ void lap_small_kernel(const int* __restrict__ row_ptr, const int2* __restrict__ csr,
                                 const float* __restrict__ x, float* __restrict__ xl) {
    int node = blockIdx.x * 16 + (threadIdx.x >> 4);
    int f = threadIdx.x & 15;
    if (node >= NN) return;
    int b = row_ptr[node], e = row_ptr[node + 1];
    float acc = 0.0f;
    for (int p = b; p < e; p++) {
        int2 ed = csr[p];
        float w = __int_as_float(ed.y);
        if (f < 12) acc += w * x[(size_t)ed.x*12 + f];
    }
    if (f < 12) xl[(size_t)node*12 + f] = acc;
}

// hl = L_hat @ h  for F=128; 32 threads (float4) per node, 8 nodes per block.
// 2-way unrolled with dual accumulators for memory-level parallelism.
__global__ void lap_big_kernel(const int* __restrict__ row_ptr, const int2* __restrict__ csr,
                               const float* __restrict__ hin, float* __restrict__ hout) {
    int node = blockIdx.x * 8 + threadIdx.y;
    if (node >= NN) return;
    int f = threadIdx.x;           // float4 lane: 0..31
    const float4* h4 = (const float4*)hin;
    float4 acc0 = make_float4(0.f, 0.f, 0.f, 0.f);
    float4 acc1 = make_float4(0.f, 0.f, 0.f, 0.f);
    int b = row_ptr[node], e = row_ptr[node + 1];
    int p = b;
    for (; p + 1 < e; p += 2) {
        int2 e0 = csr[p];
        int2 e1 = csr[p + 1];
        float w0 = __int_as_float(e0.y);
        float w1 = __int_as_float(e1.y);
        float4 v0 = h4[(size_t)e0.x*32 + f];
        float4 v1 = h4[(size_t)e1.x*32 + f];
        acc0.x += w0 * v0.x; acc0.y += w0 * v0.y; acc0.z += w0 * v0.z; acc0.w += w0 * v0.w;
        acc1.x += w1 * v1.x; acc1.y += w1 * v1.y; acc1.z += w1 * v1.z; acc1.w += w1 * v1.w;
    }
    if (p < e) {
        int2 e0 = csr[p];
        float w0 = __int_as_float(e0.y);
        float4 v0 = h4[(size_t)e0.x*32 + f];
        acc0.x += w0 * v0.x; acc0.y += w0 * v0.y; acc0.z += w0 * v0.z; acc0.w += w0 * v0.w;
    }
    acc0.x += acc1.x; acc0.y += acc1.y; acc0.z += acc1.z; acc0.w += acc1.w;
    ((float4*)hout)[(size_t)node*32 + f] = acc0;
}

__device__ __forceinline__ float2 loadA2(const float* __restrict__ x, const float* __restrict__ xl,
                                         const float* __restrict__ a2, const float* __restrict__ a3,
                                         int row, int k) {
    if (k < 12)  return *(const float2*)(x  + (size_t)row*12  + k);
    if (k < 24)  return *(const float2*)(xl + (size_t)row*12  + (k - 12));
    if (k < 152) return *(const float2*)(a2 + (size_t)row*128 + (k - 24));
    return *(const float2*)(a3 + (size_t)row*128 + (k - 152));
}

// Fused GEMM: out = [x|xl|a2|a3] @ W + bias, with epilogue.
// EPI==0 (stage A, NOUT=256): cols<128 -> z = sigmoid(v) into p0; cols>=128 -> hr = p2*sigmoid(v) into p1.
// EPI==1 (stage B, NOUT=128): h_tilde = tanh(v); p1 (=h) <- p0(z)*h + (1-z)*h_tilde.
template<int NOUT, int EPI>
__global__ __launch_bounds__(256)
void gemm_kernel(const float* __restrict__ x, const float* __restrict__ xl,
                 const float* __restrict__ a2, const float* __restrict__ a3,
                 const float* __restrict__ W, const float* __restrict__ bias,
                 float* __restrict__ p0, float* __restrict__ p1,
                 const float* __restrict__ p2)
{
    __shared__ float As[BK][BM];
    __shared__ float Bs[BK][BN];
    const int tid = threadIdx.x;
    const int row0 = blockIdx.x * BM;
    const int col0 = blockIdx.y * BN;
    const int tn_g = tid & 31;   // 32 col groups x4
    const int tm_g = tid >> 5;   // 8 row groups x8
    const int lm = tid >> 2;     // A-load row 0..63
    const int kp = (tid & 3) * 2;// A-load k-pair
    int arow = row0 + lm; if (arow >= NN) arow = NN - 1;
    const int kb = tid >> 5;     // B-load k 0..7
    const int cb = (tid & 31) * 4;

    float acc[8][4];
    #pragma unroll
    for (int i = 0; i < 8; i++) { acc[i][0]=0.f; acc[i][1]=0.f; acc[i][2]=0.f; acc[i][3]=0.f; }

    for (int k0 = 0; k0 < KTOT; k0 += BK) {
        float2 av = loadA2(x, xl, a2, a3, arow, k0 + kp);
        float4 bv = *(const float4*)(W + (size_t)(k0 + kb) * NOUT + col0 + cb);
        __syncthreads();
        As[kp][lm]     = av.x;
        As[kp + 1][lm] = av.y;
        *(float4*)(&Bs[kb][cb]) = bv;
        __syncthreads();
        #pragma unroll
        for (int kk = 0; kk < BK; kk++) {
            float4 a0 = *(const float4*)(&As[kk][tm_g*8]);
            float4 a1 = *(const float4*)(&As[kk][tm_g*8 + 4]);
            float4 b  = *(const float4*)(&Bs[kk][tn_g*4]);
            float av_[8] = {a0.x, a0.y, a0.z, a0.w, a1.x, a1.y, a1.z, a1.w};
            float bv_[4] = {b.x, b.y, b.z, b.w};
            #pragma unroll
            for (int i = 0; i < 8; i++)
                #pragma unroll
                for (int j = 0; j < 4; j++)
                    acc[i][j] += av_[i] * bv_[j];
        }
    }

    #pragma unroll
    for (int i = 0; i < 8; i++) {
        int row = row0 + tm_g*8 + i;
        if (row >= NN) continue;
        #pragma unroll
        for (int j = 0; j < 4; j++) {
            int col = col0 + tn_g*4 + j;
            float v = acc[i][j] + bias[col];
            if (EPI == 0) {
                float s = fast_sigmoid(v);
                if (col < HID) {
                    p0[(size_t)row*HID + col] = s;                      // z
                } else {
                    int c = col - HID;
                    p1[(size_t)row*HID + c] = p2[(size_t)row*HID + c] * s;  // hr = h*r
                }
            } else {
                float ht = fast_tanh(v);
                float zz   = p0[(size_t)row*HID + col];
                float hold = p1[(size_t)row*HID + col];
                p1[(size_t)row*HID + col] = zz*hold + (1.0f - zz)*ht;   // h update
            }
        }
    }
}

// u = h @ W_head + b_head ; 64 lanes per node (2 h-elems each), shfl reduce
__global__ void head_kernel(const float* __restrict__ h, const float* __restrict__ Whead,
                            const float* __restrict__ bhead, float* __restrict__ out) {
    int node = blockIdx.x * 4 + (threadIdx.x >> 6);
    int lane = threadIdx.x & 63;
    if (node >= NN) return;
    float h0 = h[(size_t)node*128 + lane];
    float h1 = h[(size_t)node*128 + 64 + lane];
    float p[3];
    #pragma unroll
    for (int j = 0; j < 3; j++)
        p[j] = h0 * Whead[lane*3 + j] + h1 * Whead[(64 + lane)*3 + j];
    #pragma unroll
    for (int off = 32; off > 0; off >>= 1) {
        p[0] += __shfl_down(p[0], off);
        p[1] += __shfl_down(p[1], off);
        p[2] += __shfl_down(p[2], off);
    }
    if (lane == 0) {
        out[(size_t)node*3 + 0] = p[0] + bhead[0];
        out[(size_t)node*3 + 1] = p[1] + bhead[1];
        out[(size_t)node*3 + 2] = p[2] + bhead[2];
    }
}

// ---------------- host launch ----------------

extern "C" void kernel_launch(void* const* d_in, const int* in_sizes, int n_in,
                              void* d_out, int out_size, void* d_ws, size_t ws_size,
                              hipStream_t stream) {
    const float* X_seq  = (const float*)d_in[0];   // [24,50000,11]
    const int*   eidx   = (const int*)  d_in[1];   // [2,800000]
    const float* Wx     = (const float*)d_in[2];   // [3,2,11,128]
    const float* bx     = (const float*)d_in[3];   // [3,128]
    const float* Wh     = (const float*)d_in[4];   // [3,2,128,128]
    const float* bh     = (const float*)d_in[5];   // [3,128]
    const float* Whead  = (const float*)d_in[6];   // [128,3]
    const float* bhead  = (const float*)d_in[7];   // [3]
    float* out = (float*)d_out;                    // [24,50000,3]

    const int* src = eidx;
    const int* dst = eidx + EE;

    // carve workspace
    char* base = (char*)d_ws;
    size_t off = 0;
    auto carve = [&](size_t bytes) -> void* {
        void* p = base + off;
        off += (bytes + 255) & ~(size_t)255;
        return p;
    };
    int*   deg_i   = (int*)  carve((size_t)NN * 4);
    int*   cnt     = (int*)  carve((size_t)NN * 4);
    int*   fillp   = (int*)  carve((size_t)NN * 4);
    int*   row_ptr = (int*)  carve((size_t)(NN + 1) * 4);
    float* dinv    = (float*)carve((size_t)NN * 4);
    int2*  csr     = (int2*) carve((size_t)EE * 8);
    float* WA      = (float*)carve((size_t)280 * 256 * 4);
    float* biasA   = (float*)carve(256 * 4);
    float* WB      = (float*)carve((size_t)280 * 128 * 4);
    float* biasB   = (float*)carve(128 * 4);
    float* xbuf    = (float*)carve((size_t)NN * 12 * 4);
    float* xlbuf   = (float*)carve((size_t)NN * 12 * 4);
    float* hbuf    = (float*)carve((size_t)NN * 128 * 4);
    float* hlbuf   = (float*)carve((size_t)NN * 128 * 4);
    float* hrbuf   = (float*)carve((size_t)NN * 128 * 4);
    float* zbuf    = (float*)carve((size_t)NN * 128 * 4);
    float* hrlbuf  = hlbuf;  // alias: hlbuf dead after stage-A GEMM; reused for lap(hr)
    (void)ws_size; (void)n_in; (void)in_sizes; (void)out_size;

    // zero init
    hipMemsetAsync(deg_i, 0, (size_t)NN * 4, stream);
    hipMemsetAsync(cnt,   0, (size_t)NN * 4, stream);
    hipMemsetAsync(fillp, 0, (size_t)NN * 4, stream);
    hipMemsetAsync(hbuf,  0, (size_t)NN * 128 * 4, stream);

    // preprocessing
    count_deg_kernel<<<(EE + 255) / 256, 256, 0, stream>>>(src, dst, deg_i, cnt);
    dinv_kernel<<<(NN + 255) / 256, 256, 0, stream>>>(deg_i, dinv);
    scan_kernel<<<1, 1024, 0, stream>>>(cnt, row_ptr);
    fill_csr_kernel<<<(EE + 255) / 256, 256, 0, stream>>>(src, dst, row_ptr, fillp, dinv, csr);
    {
        int total = 280*256 + 280*128 + 256 + 128;
        pack_weights_kernel<<<(total + 255) / 256, 256, 0, stream>>>(Wx, bx, Wh, bh, WA, biasA, WB, biasB);
    }

    const int gridN256 = (NN + 255) / 256;
    const dim3 gridGA((NN + BM - 1) / BM, 2);
    const dim3 gridGB((NN + BM - 1) / BM, 1);

    for (int t = 0; t < TT; t++) {
        if (t == 0) {
            copy_x0_kernel<<<gridN256, 256, 0, stream>>>(X_seq, xbuf);
        } else {
            const float* Xt   = X_seq + (size_t)t * NN * 11;
            const float* Xtm1 = X_seq + (size_t)(t - 1) * NN * 11;
            const float* pos  = out + (size_t)(t - 1) * NN * 3;
            const float* prevbase;
            int pstride, poff;
            if (t == 1) { prevbase = X_seq; pstride = 11; poff = 3; }          // X_seq[0][:,3:6]
            else        { prevbase = out + (size_t)(t - 2) * NN * 3; pstride = 3; poff = 0; }
            build_x_kernel<<<gridN256, 256, 0, stream>>>(Xt, Xtm1, pos, prevbase, pstride, poff, xbuf);
        }

        lap_small_kernel<<<(NN + 15) / 16, 256, 0, stream>>>(row_ptr, csr, xbuf, xlbuf);
        lap_big_kernel<<<(NN + 7) / 8, dim3(32, 8), 0, stream>>>(row_ptr, csr, hbuf, hlbuf);

        // stage A: z and hr
        gemm_kernel<256, 0><<<gridGA, 256, 0, stream>>>(xbuf, xlbuf, hbuf, hlbuf, WA, biasA,
                                                        zbuf, hrbuf, hbuf);
        // lap of hr (reuses hlbuf storage)
        lap_big_kernel<<<(NN + 7) / 8, dim3(32, 8), 0, stream>>>(row_ptr, csr, hrbuf, hrlbuf);

        // stage B: h_tilde and h update (in place on hbuf)
        gemm_kernel<128, 1><<<gridGB, 256, 0, stream>>>(xbuf, xlbuf, hrbuf, hrlbuf, WB, biasB,
                                                        zbuf, hbuf, nullptr);

        // head: u_t
        head_kernel<<<(NN + 3) / 4, 256, 0, stream>>>(hbuf, Whead, bhead, out + (size_t)t * NN * 3);
    }
}

// Round 5
// 8144.721 us; speedup vs baseline: 1.0164x; 1.0164x over previous
//
#include <hip/hip_runtime.h>
#include <math.h>

#define NN 50000
#define EE 800000
#define TT 24
#define INF 11
#define HID 128

static constexpr int KTOT = 280;   // 12(x) + 12(xl) + 128(h) + 128(hl), padded
#define BM 64
#define BN 128
#define BK 8
static constexpr int NSTEP = KTOT / BK;  // 35

// fast device math: v_exp_f32-based sigmoid/tanh, saturation-safe
__device__ __forceinline__ float fast_sigmoid(float v) {
    float e = __expf(-v);                       // v<<0 -> inf, v>>0 -> 0
    return __builtin_amdgcn_rcpf(1.0f + e);     // rcp(inf)=0, rcp(1)=1
}
__device__ __forceinline__ float fast_tanh(float v) {
    float e2 = __expf(2.0f * v);                // v>>0 -> inf, v<<0 -> 0
    return 1.0f - 2.0f * __builtin_amdgcn_rcpf(e2 + 1.0f);  // -> +1 / -1
}

// ---------------- preprocessing kernels ----------------

__global__ void count_deg_kernel(const int* __restrict__ src, const int* __restrict__ dst,
                                 int* __restrict__ deg_src, int* __restrict__ cnt_dst) {
    int e = blockIdx.x * blockDim.x + threadIdx.x;
    if (e < EE) {
        atomicAdd(&deg_src[src[e]], 1);
        atomicAdd(&cnt_dst[dst[e]], 1);
    }
}

__global__ void dinv_kernel(const int* __restrict__ deg, float* __restrict__ dinv) {
    int i = blockIdx.x * blockDim.x + threadIdx.x;
    if (i < NN) {
        int d = deg[i];
        dinv[i] = (d > 0) ? 1.0f / sqrtf((float)d) : 0.0f;
    }
}

// single-block scan over cnt -> exclusive prefix (row_ptr), row_ptr[NN] = E
__global__ void scan_kernel(const int* __restrict__ cnt, int* __restrict__ row_ptr) {
    __shared__ int buf[2][1024];
    __shared__ int carry_s;
    int tid = threadIdx.x;
    if (tid == 0) carry_s = 0;
    __syncthreads();
    for (int base = 0; base < NN; base += 1024) {
        int i = base + tid;
        int v = (i < NN) ? cnt[i] : 0;
        int pb = 0;
        buf[0][tid] = v;
        __syncthreads();
        for (int off = 1; off < 1024; off <<= 1) {
            int t = buf[pb][tid] + ((tid >= off) ? buf[pb][tid - off] : 0);
            buf[pb ^ 1][tid] = t;
            pb ^= 1;
            __syncthreads();
        }
        int incl = buf[pb][tid];
        int carry = carry_s;
        if (i < NN) row_ptr[i] = carry + incl - v;
        __syncthreads();
        if (tid == 0) carry_s = carry + buf[pb][1023];
        __syncthreads();
    }
    if (tid == 0) row_ptr[NN] = carry_s;
}

// CSR entry packed as int2 {src, float_bits(w)} -> one 8B load per edge in the laps
__global__ void fill_csr_kernel(const int* __restrict__ src, const int* __restrict__ dst,
                                const int* __restrict__ row_ptr, int* __restrict__ fillp,
                                const float* __restrict__ dinv,
                                int2* __restrict__ csr) {
    int e = blockIdx.x * blockDim.x + threadIdx.x;
    if (e < EE) {
        int s = src[e], d = dst[e];
        int p = row_ptr[d] + atomicAdd(&fillp[d], 1);
        float w = -(dinv[s] * dinv[d]);
        csr[p] = make_int2(s, __float_as_int(w));
    }
}

// pack Wx/Wh into WA [280][256] (gates z,r) and WB [280][128] (gate h~), biases summed
__global__ void pack_weights_kernel(const float* __restrict__ Wx, const float* __restrict__ bx,
                                    const float* __restrict__ Wh, const float* __restrict__ bh,
                                    float* __restrict__ WA, float* __restrict__ biasA,
                                    float* __restrict__ WB, float* __restrict__ biasB) {
    int idx = blockIdx.x * blockDim.x + threadIdx.x;
    const int NA = 280 * 256, NB = 280 * 128;
    if (idx < NA) {
        int k = idx / 256, j = idx % 256;
        int g = j >> 7, jj = j & 127;
        float v = 0.0f;
        if (k < 12)       { if (k < 11)      v = Wx[((g*2 + 0)*11 + k)      * 128 + jj]; }
        else if (k < 24)  { int kk = k - 12; if (kk < 11) v = Wx[((g*2 + 1)*11 + kk) * 128 + jj]; }
        else if (k < 152) { int kk = k - 24;  v = Wh[((g*2 + 0)*128 + kk) * 128 + jj]; }
        else              { int kk = k - 152; v = Wh[((g*2 + 1)*128 + kk) * 128 + jj]; }
        WA[idx] = v;
    } else if (idx < NA + NB) {
        int t = idx - NA;
        int k = t / 128, jj = t % 128;
        float v = 0.0f;
        if (k < 12)       { if (k < 11)      v = Wx[(4*11 + k)  * 128 + jj]; }
        else if (k < 24)  { int kk = k - 12; if (kk < 11) v = Wx[(5*11 + kk) * 128 + jj]; }
        else if (k < 152) { int kk = k - 24;  v = Wh[(4*128 + kk) * 128 + jj]; }
        else              { int kk = k - 152; v = Wh[(5*128 + kk) * 128 + jj]; }
        WB[t] = v;
    } else if (idx < NA + NB + 256) {
        int j = idx - (NA + NB);
        int g = j >> 7, jj = j & 127;
        biasA[j] = bx[g*128 + jj] + bh[g*128 + jj];
    } else if (idx < NA + NB + 256 + 128) {
        int jj = idx - (NA + NB + 256);
        biasB[jj] = bx[2*128 + jj] + bh[2*128 + jj];
    }
}

// ---------------- per-step kernels ----------------

__global__ void copy_x0_kernel(const float* __restrict__ X0, float* __restrict__ x) {
    int i = blockIdx.x * blockDim.x + threadIdx.x;
    if (i < NN) {
        #pragma unroll
        for (int c = 0; c < 11; c++) x[i*12 + c] = X0[i*11 + c];
        x[i*12 + 11] = 0.0f;
    }
}

// x = [X_t[:, :3], pos, X_t[:, 6:8], (pos - prev)/dt]  (pad col 11 = 0)
__global__ void build_x_kernel(const float* __restrict__ Xt, const float* __restrict__ Xtm1,
                               const float* __restrict__ pos, const float* __restrict__ prevbase,
                               int prev_stride, int prev_off, float* __restrict__ x) {
    int i = blockIdx.x * blockDim.x + threadIdx.x;
    if (i >= NN) return;
    const float* xo = Xt + (size_t)i * 11;
    float tnow  = xo[6];
    float tprev = Xtm1[(size_t)i * 11 + 6];
    float inv = 1.0f / (tnow - tprev);
    float p0 = pos[(size_t)i*3 + 0], p1 = pos[(size_t)i*3 + 1], p2 = pos[(size_t)i*3 + 2];
    const float* pp = prevbase + (size_t)i * prev_stride + prev_off;
    float q0 = pp[0], q1 = pp[1], q2 = pp[2];
    float* xr = x + (size_t)i * 12;
    xr[0] = xo[0]; xr[1] = xo[1]; xr[2] = xo[2];
    xr[3] = p0;    xr[4] = p1;    xr[5] = p2;
    xr[6] = tnow;  xr[7] = xo[7];
    xr[8] = (p0 - q0) * inv; xr[9] = (p1 - q1) * inv; xr[10] = (p2 - q2) * inv;
    xr[11] = 0.0f;
}

// xl = L_hat @ x  for F=12 (padded); 16 threads per node
__global__ void lap_small_kernel(const int* __restrict__ row_ptr, const int2* __restrict__ csr,
                                 const float* __restrict__ x, float* __restrict__ xl) {
    int node = blockIdx.x * 16 + (threadIdx.x >> 4);
    int f = threadIdx.x & 15;
    if (node >= NN) return;
    int b = row_ptr[node], e = row_ptr[node + 1];
    float acc = 0.0f;
    for (int p = b; p < e; p++) {
        int2 ed = csr[p];
        float w = __int_as_float(ed.y);
        if (f < 12) acc += w * x[(size_t)ed.x*12 + f];
    }
    if (f < 12) xl[(size_t)node*12 + f] = acc;
}

// hl = L_hat @ h  for F=128. One node per 64-lane wave: lanes = 2 edges x 32 f-lanes
// (float4 each). 4 edges in flight (pair + unroll-2, dual accumulators); shfl_xor(32)
// merges the two edge-halves. No intra-wave degree divergence.
__global__ __launch_bounds__(256)
void lap_big_kernel(const int* __restrict__ row_ptr, const int2* __restrict__ csr,
                    const float* __restrict__ hin, float* __restrict__ hout) {
    int tid  = threadIdx.x;
    int node = blockIdx.x * 4 + (tid >> 6);
    if (node >= NN) return;
    int eo = (tid >> 5) & 1;   // which edge of the pair
    int f  = tid & 31;         // float4 lane
    const float4* h4 = (const float4*)hin;
    float4 acc0 = make_float4(0.f, 0.f, 0.f, 0.f);
    float4 acc1 = make_float4(0.f, 0.f, 0.f, 0.f);
    int b = row_ptr[node], e = row_ptr[node + 1];
    int p = b;
    for (; p + 3 < e; p += 4) {
        int2 ea = csr[p + eo];
        int2 eb = csr[p + 2 + eo];
        float wa = __int_as_float(ea.y);
        float wb = __int_as_float(eb.y);
        float4 va = h4[(size_t)ea.x*32 + f];
        float4 vb = h4[(size_t)eb.x*32 + f];
        acc0.x += wa * va.x; acc0.y += wa * va.y; acc0.z += wa * va.z; acc0.w += wa * va.w;
        acc1.x += wb * vb.x; acc1.y += wb * vb.y; acc1.z += wb * vb.z; acc1.w += wb * vb.w;
    }
    for (; p + 1 < e; p += 2) {
        int2 ea = csr[p + eo];
        float wa = __int_as_float(ea.y);
        float4 va = h4[(size_t)ea.x*32 + f];
        acc0.x += wa * va.x; acc0.y += wa * va.y; acc0.z += wa * va.z; acc0.w += wa * va.w;
    }
    if (p < e && eo == 0) {    // odd tail edge
        int2 ea = csr[p];
        float wa = __int_as_float(ea.y);
        float4 va = h4[(size_t)ea.x*32 + f];
        acc0.x += wa * va.x; acc0.y += wa * va.y; acc0.z += wa * va.z; acc0.w += wa * va.w;
    }
    acc0.x += acc1.x; acc0.y += acc1.y; acc0.z += acc1.z; acc0.w += acc1.w;
    acc0.x += __shfl_xor(acc0.x, 32);
    acc0.y += __shfl_xor(acc0.y, 32);
    acc0.z += __shfl_xor(acc0.z, 32);
    acc0.w += __shfl_xor(acc0.w, 32);
    if (eo == 0)
        ((float4*)hout)[(size_t)node*32 + f] = acc0;
}

__device__ __forceinline__ float2 loadA2(const float* __restrict__ x, const float* __restrict__ xl,
                                         const float* __restrict__ a2, const float* __restrict__ a3,
                                         int row, int k) {
    if (k < 12)  return *(const float2*)(x  + (size_t)row*12  + k);
    if (k < 24)  return *(const float2*)(xl + (size_t)row*12  + (k - 12));
    if (k < 152) return *(const float2*)(a2 + (size_t)row*128 + (k - 24));
    return *(const float2*)(a3 + (size_t)row*128 + (k - 152));
}

// Fused GEMM: out = [x|xl|a2|a3] @ W + bias, with epilogue.
// Double-buffered LDS, register prefetch, ONE barrier per K-step.
// EPI==0 (stage A, NOUT=256): cols<128 -> z = sigmoid(v) into p0; cols>=128 -> hr = p2*sigmoid(v) into p1.
// EPI==1 (stage B, NOUT=128): h_tilde = tanh(v); p1 (=h) <- p0(z)*h + (1-z)*h_tilde.
template<int NOUT, int EPI>
__global__ __launch_bounds__(256)
void gemm_kernel(const float* __restrict__ x, const float* __restrict__ xl,
                 const float* __restrict__ a2, const float* __restrict__ a3,
                 const float* __restrict__ W, const float* __restrict__ bias,
                 float* __restrict__ p0, float* __restrict__ p1,
                 const float* __restrict__ p2)
{
    __shared__ float As[2][BK][BM];
    __shared__ float Bs[2][BK][BN];
    const int tid = threadIdx.x;
    const int row0 = blockIdx.x * BM;
    const int col0 = blockIdx.y * BN;
    const int tn_g = tid & 31;   // 32 col groups x4
    const int tm_g = tid >> 5;   // 8 row groups x8
    const int lm = tid >> 2;     // A-load row 0..63
    const int kp = (tid & 3) * 2;// A-load k-pair
    int arow = row0 + lm; if (arow >= NN) arow = NN - 1;
    const int kb = tid >> 5;     // B-load k 0..7
    const int cb = (tid & 31) * 4;

    float acc[8][4];
    #pragma unroll
    for (int i = 0; i < 8; i++) { acc[i][0]=0.f; acc[i][1]=0.f; acc[i][2]=0.f; acc[i][3]=0.f; }

    // prologue: tile 0 -> LDS[0]
    float2 av = loadA2(x, xl, a2, a3, arow, kp);
    float4 bv = *(const float4*)(W + (size_t)kb * NOUT + col0 + cb);
    As[0][kp][lm]     = av.x;
    As[0][kp + 1][lm] = av.y;
    *(float4*)(&Bs[0][kb][cb]) = bv;
    __syncthreads();

    int bb = 0;
    for (int s = 0; s < NSTEP; s++) {
        // prefetch next tile into registers (global latency hidden under compute)
        float2 av2; float4 bv2;
        if (s + 1 < NSTEP) {
            int kn = (s + 1) * BK;
            av2 = loadA2(x, xl, a2, a3, arow, kn + kp);
            bv2 = *(const float4*)(W + (size_t)(kn + kb) * NOUT + col0 + cb);
        }
        #pragma unroll
        for (int kk = 0; kk < BK; kk++) {
            float4 a0 = *(const float4*)(&As[bb][kk][tm_g*8]);
            float4 a1 = *(const float4*)(&As[bb][kk][tm_g*8 + 4]);
            float4 b  = *(const float4*)(&Bs[bb][kk][tn_g*4]);
            float av_[8] = {a0.x, a0.y, a0.z, a0.w, a1.x, a1.y, a1.z, a1.w};
            float bv_[4] = {b.x, b.y, b.z, b.w};
            #pragma unroll
            for (int i = 0; i < 8; i++)
                #pragma unroll
                for (int j = 0; j < 4; j++)
                    acc[i][j] += av_[i] * bv_[j];
        }
        if (s + 1 < NSTEP) {
            As[bb ^ 1][kp][lm]     = av2.x;
            As[bb ^ 1][kp + 1][lm] = av2.y;
            *(float4*)(&Bs[bb ^ 1][kb][cb]) = bv2;
            __syncthreads();
            bb ^= 1;
        }
    }

    #pragma unroll
    for (int i = 0; i < 8; i++) {
        int row = row0 + tm_g*8 + i;
        if (row >= NN) continue;
        #pragma unroll
        for (int j = 0; j < 4; j++) {
            int col = col0 + tn_g*4 + j;
            float v = acc[i][j] + bias[col];
            if (EPI == 0) {
                float s = fast_sigmoid(v);
                if (col < HID) {
                    p0[(size_t)row*HID + col] = s;                      // z
                } else {
                    int c = col - HID;
                    p1[(size_t)row*HID + c] = p2[(size_t)row*HID + c] * s;  // hr = h*r
                }
            } else {
                float ht = fast_tanh(v);
                float zz   = p0[(size_t)row*HID + col];
                float hold = p1[(size_t)row*HID + col];
                p1[(size_t)row*HID + col] = zz*hold + (1.0f - zz)*ht;   // h update
            }
        }
    }
}

// u = h @ W_head + b_head ; 64 lanes per node (2 h-elems each), shfl reduce
__global__ void head_kernel(const float* __restrict__ h, const float* __restrict__ Whead,
                            const float* __restrict__ bhead, float* __restrict__ out) {
    int node = blockIdx.x * 4 + (threadIdx.x >> 6);
    int lane = threadIdx.x & 63;
    if (node >= NN) return;
    float h0 = h[(size_t)node*128 + lane];
    float h1 = h[(size_t)node*128 + 64 + lane];
    float p[3];
    #pragma unroll
    for (int j = 0; j < 3; j++)
        p[j] = h0 * Whead[lane*3 + j] + h1 * Whead[(64 + lane)*3 + j];
    #pragma unroll
    for (int off = 32; off > 0; off >>= 1) {
        p[0] += __shfl_down(p[0], off);
        p[1] += __shfl_down(p[1], off);
        p[2] += __shfl_down(p[2], off);
    }
    if (lane == 0) {
        out[(size_t)node*3 + 0] = p[0] + bhead[0];
        out[(size_t)node*3 + 1] = p[1] + bhead[1];
        out[(size_t)node*3 + 2] = p[2] + bhead[2];
    }
}

// ---------------- host launch ----------------

extern "C" void kernel_launch(void* const* d_in, const int* in_sizes, int n_in,
                              void* d_out, int out_size, void* d_ws, size_t ws_size,
                              hipStream_t stream) {
    const float* X_seq  = (const float*)d_in[0];   // [24,50000,11]
    const int*   eidx   = (const int*)  d_in[1];   // [2,800000]
    const float* Wx     = (const float*)d_in[2];   // [3,2,11,128]
    const float* bx     = (const float*)d_in[3];   // [3,128]
    const float* Wh     = (const float*)d_in[4];   // [3,2,128,128]
    const float* bh     = (const float*)d_in[5];   // [3,128]
    const float* Whead  = (const float*)d_in[6];   // [128,3]
    const float* bhead  = (const float*)d_in[7];   // [3]
    float* out = (float*)d_out;                    // [24,50000,3]

    const int* src = eidx;
    const int* dst = eidx + EE;

    // carve workspace
    char* base = (char*)d_ws;
    size_t off = 0;
    auto carve = [&](size_t bytes) -> void* {
        void* p = base + off;
        off += (bytes + 255) & ~(size_t)255;
        return p;
    };
    int*   deg_i   = (int*)  carve((size_t)NN * 4);
    int*   cnt     = (int*)  carve((size_t)NN * 4);
    int*   fillp   = (int*)  carve((size_t)NN * 4);
    int*   row_ptr = (int*)  carve((size_t)(NN + 1) * 4);
    float* dinv    = (float*)carve((size_t)NN * 4);
    int2*  csr     = (int2*) carve((size_t)EE * 8);
    float* WA      = (float*)carve((size_t)280 * 256 * 4);
    float* biasA   = (float*)carve(256 * 4);
    float* WB      = (float*)carve((size_t)280 * 128 * 4);
    float* biasB   = (float*)carve(128 * 4);
    float* xbuf    = (float*)carve((size_t)NN * 12 * 4);
    float* xlbuf   = (float*)carve((size_t)NN * 12 * 4);
    float* hbuf    = (float*)carve((size_t)NN * 128 * 4);
    float* hlbuf   = (float*)carve((size_t)NN * 128 * 4);
    float* hrbuf   = (float*)carve((size_t)NN * 128 * 4);
    float* zbuf    = (float*)carve((size_t)NN * 128 * 4);
    float* hrlbuf  = hlbuf;  // alias: hlbuf dead after stage-A GEMM; reused for lap(hr)
    (void)ws_size; (void)n_in; (void)in_sizes; (void)out_size;

    // zero init
    hipMemsetAsync(deg_i, 0, (size_t)NN * 4, stream);
    hipMemsetAsync(cnt,   0, (size_t)NN * 4, stream);
    hipMemsetAsync(fillp, 0, (size_t)NN * 4, stream);
    hipMemsetAsync(hbuf,  0, (size_t)NN * 128 * 4, stream);

    // preprocessing
    count_deg_kernel<<<(EE + 255) / 256, 256, 0, stream>>>(src, dst, deg_i, cnt);
    dinv_kernel<<<(NN + 255) / 256, 256, 0, stream>>>(deg_i, dinv);
    scan_kernel<<<1, 1024, 0, stream>>>(cnt, row_ptr);
    fill_csr_kernel<<<(EE + 255) / 256, 256, 0, stream>>>(src, dst, row_ptr, fillp, dinv, csr);
    {
        int total = 280*256 + 280*128 + 256 + 128;
        pack_weights_kernel<<<(total + 255) / 256, 256, 0, stream>>>(Wx, bx, Wh, bh, WA, biasA, WB, biasB);
    }

    const int gridN256 = (NN + 255) / 256;
    const dim3 gridGA((NN + BM - 1) / BM, 2);
    const dim3 gridGB((NN + BM - 1) / BM, 1);

    for (int t = 0; t < TT; t++) {
        if (t == 0) {
            copy_x0_kernel<<<gridN256, 256, 0, stream>>>(X_seq, xbuf);
        } else {
            const float* Xt   = X_seq + (size_t)t * NN * 11;
            const float* Xtm1 = X_seq + (size_t)(t - 1) * NN * 11;
            const float* pos  = out + (size_t)(t - 1) * NN * 3;
            const float* prevbase;
            int pstride, poff;
            if (t == 1) { prevbase = X_seq; pstride = 11; poff = 3; }          // X_seq[0][:,3:6]
            else        { prevbase = out + (size_t)(t - 2) * NN * 3; pstride = 3; poff = 0; }
            build_x_kernel<<<gridN256, 256, 0, stream>>>(Xt, Xtm1, pos, prevbase, pstride, poff, xbuf);
        }

        lap_small_kernel<<<(NN + 15) / 16, 256, 0, stream>>>(row_ptr, csr, xbuf, xlbuf);
        lap_big_kernel<<<(NN + 3) / 4, 256, 0, stream>>>(row_ptr, csr, hbuf, hlbuf);

        // stage A: z and hr
        gemm_kernel<256, 0><<<gridGA, 256, 0, stream>>>(xbuf, xlbuf, hbuf, hlbuf, WA, biasA,
                                                        zbuf, hrbuf, hbuf);
        // lap of hr (reuses hlbuf storage)
        lap_big_kernel<<<(NN + 3) / 4, 256, 0, stream>>>(row_ptr, csr, hrbuf, hrlbuf);

        // stage B: h_tilde and h update (in place on hbuf)
        gemm_kernel<128, 1><<<gridGB, 256, 0, stream>>>(xbuf, xlbuf, hrbuf, hrlbuf, WB, biasB,
                                                        zbuf, hbuf, nullptr);

        // head: u_t
        head_kernel<<<(NN + 3) / 4, 256, 0, stream>>>(hbuf, Whead, bhead, out + (size_t)t * NN * 3);
    }
}